// Round 2
// baseline (698.586 us; speedup 1.0000x reference)
//
#include <hip/hip_runtime.h>
#include <cstdint>

#define DEVINL __device__ __forceinline__

typedef uint16_t u16;
typedef uint32_t u32;
typedef __attribute__((ext_vector_type(8))) short short8;
typedef __attribute__((ext_vector_type(4))) float floatx4;
typedef const __attribute__((address_space(1))) void* gas_ptr;
typedef __attribute__((address_space(3))) void* las_ptr;

DEVINL u16 f2bf(float f) {
  u32 u = __float_as_uint(f);
  u32 r = u + 0x7FFFu + ((u >> 16) & 1u);   // RNE
  return (u16)(r >> 16);
}
DEVINL float bf2f(u16 b) { return __uint_as_float((u32)b << 16); }

// ---------- row_start[n] = lower_bound(dst, n) over sorted dst ----------
__global__ void rowstart_kernel(const int* __restrict__ dst, int* __restrict__ rs,
                                int N, int E) {
  int n = blockIdx.x * blockDim.x + threadIdx.x;
  if (n > N) return;
  int lo = 0, hi = E;
  while (lo < hi) { int mid = (lo + hi) >> 1; if (dst[mid] < n) lo = mid + 1; else hi = mid; }
  rs[n] = lo;
}

// ---------- f32 -> split-bf16 planar: A'=[hi|hi|lo], B'=[hi|lo|hi], row len 3K ----------
template<bool IsA>
__global__ __launch_bounds__(256)
void split_kernel(const float* __restrict__ in, u16* __restrict__ out, int MK, int K) {
  int idx = blockIdx.x * blockDim.x + threadIdx.x;
  if (idx >= MK) return;
  int m = idx / K, k = idx - m * K;
  float a = in[idx];
  u16 h = f2bf(a);
  u16 lo = f2bf(a - bf2f(h));
  size_t base = (size_t)m * 3 * K;
  if (IsA) { out[base + k] = h;  out[base + K + k] = h;  out[base + 2 * K + k] = lo; }
  else     { out[base + k] = h;  out[base + K + k] = lo; out[base + 2 * K + k] = h;  }
}

// ---------- GEMM: C[M,Nout](f32) = A'[M,K'] * B'[Nout,K']^T  (split-bf16 in) ----------
// BM=128, BK=32, 256 threads (4 waves); wave w owns rows [32w,32w+32).
template<int BN>
__global__ __launch_bounds__(256)
void gemm_bt_kernel(const u16* __restrict__ A, const u16* __restrict__ B,
                    float* __restrict__ C, int M, int Nout, int K)
{
  constexpr int BM = 128, BK = 32;
  __shared__ __align__(16) u16 As[BM * BK];
  __shared__ __align__(16) u16 Bs[BN * BK];
  const int tid  = threadIdx.x;
  const int wave = tid >> 6;
  const int lane = tid & 63;
  const int quad = lane >> 4;
  const int l16  = lane & 15;
  const int rowBase = blockIdx.y * BM;
  const int colBase = blockIdx.x * BN;

  floatx4 acc[2][BN / 16];
  #pragma unroll
  for (int r = 0; r < 2; ++r)
    #pragma unroll
    for (int c = 0; c < BN / 16; ++c)
      acc[r][c] = (floatx4){0.f, 0.f, 0.f, 0.f};

  int aRow[2], aCol[2];
  #pragma unroll
  for (int i = 0; i < 2; ++i) {
    int flat = (2 * wave + i) * 512 + lane * 8;   // elem idx in 128x32 tile
    int r = flat >> 5;
    aCol[i] = flat & 31;
    int gr = rowBase + r;
    if (gr >= M) gr = M - 1;                      // clamp: safe load, store guarded
    aRow[i] = gr;
  }
  constexpr int BCALLS = (BN * BK) / 512;         // 4 for BN=64, 2 for BN=32
  int bRow = 0, bCol = 0;
  if (wave < BCALLS) {
    int flat = wave * 512 + lane * 8;
    bRow = colBase + (flat >> 5);
    bCol = flat & 31;
  }

  for (int k0 = 0; k0 < K; k0 += BK) {
    __syncthreads();
    #pragma unroll
    for (int i = 0; i < 2; ++i) {
      const u16* gp = A + (size_t)aRow[i] * K + (k0 + aCol[i]);
      __builtin_amdgcn_global_load_lds((gas_ptr)gp,
          (las_ptr)(As + (2 * wave + i) * 512), 16, 0, 0);
    }
    if (wave < BCALLS) {
      const u16* gp = B + (size_t)bRow * K + (k0 + bCol);
      __builtin_amdgcn_global_load_lds((gas_ptr)gp,
          (las_ptr)(Bs + wave * 512), 16, 0, 0);
    }
    __syncthreads();
    short8 a0 = *(const short8*)(As + (32 * wave + l16) * BK + quad * 8);
    short8 a1 = *(const short8*)(As + (32 * wave + 16 + l16) * BK + quad * 8);
    #pragma unroll
    for (int c = 0; c < BN / 16; ++c) {
      short8 b = *(const short8*)(Bs + (16 * c + l16) * BK + quad * 8);
      acc[0][c] = __builtin_amdgcn_mfma_f32_16x16x32_bf16(a0, b, acc[0][c], 0, 0, 0);
      acc[1][c] = __builtin_amdgcn_mfma_f32_16x16x32_bf16(a1, b, acc[1][c], 0, 0, 0);
    }
  }

  // C/D layout: col = lane&15, row = quad*4 + reg (verified m89/m91)
  #pragma unroll
  for (int rt = 0; rt < 2; ++rt)
    #pragma unroll
    for (int c = 0; c < BN / 16; ++c)
      #pragma unroll
      for (int i = 0; i < 4; ++i) {
        int gr = rowBase + 32 * wave + 16 * rt + quad * 4 + i;
        if (gr < M) {
          int gc = colBase + 16 * c + l16;
          C[(size_t)gr * Nout + gc] = acc[rt][c][i];
        }
      }
}

// ---------- el[n,h] = sum_f z[n,h,f]*al[h,f]; er likewise (all f32) ----------
template<int H, int F>
__global__ __launch_bounds__(256)
void elr_kernel(const float* __restrict__ z, const float* __restrict__ al,
                const float* __restrict__ ar, float* __restrict__ el,
                float* __restrict__ er, int N)
{
  int t = blockIdx.x * blockDim.x + threadIdx.x;
  if (t >= N * H) return;
  int h = t % H;
  const float4* zp  = (const float4*)(z + (size_t)t * F);
  const float4* alp = (const float4*)(al + h * F);
  const float4* arp = (const float4*)(ar + h * F);
  float sl = 0.f, sr = 0.f;
  #pragma unroll
  for (int i = 0; i < F / 4; ++i) {
    float4 zz = zp[i], aa = alp[i], rr = arp[i];
    sl += zz.x * aa.x + zz.y * aa.y + zz.z * aa.z + zz.w * aa.w;
    sr += zz.x * rr.x + zz.y * rr.y + zz.z * rr.z + zz.w * rr.w;
  }
  el[t] = sl;
  er[t] = sr;
}

// ---------- per-dst softmax over contiguous edge range + aggregation ----------
// SPLIT_OUT: write next layer's A' = [hi|hi|lo] (row len 3*FH) instead of f32.
template<int H, int F, int NT, bool ELU, bool SPLIT_OUT>
__global__ __launch_bounds__(NT)
void agg_kernel(const float* __restrict__ z, const float* __restrict__ el,
                const float* __restrict__ er, const int* __restrict__ src,
                const int* __restrict__ rs, float* __restrict__ fout,
                u16* __restrict__ a2out)
{
  constexpr int FH = F * H;
  constexpr int CH = 32;                 // edge chunk
  const int n = blockIdx.x;
  const int tid = threadIdx.x;
  const int s = rs[n], e_end = rs[n + 1];
  const int deg = e_end - s;
  const int c0 = 2 * tid;                // this thread's two columns
  const bool active = (c0 < FH);

  __shared__ float m_sh[H], inv_sh[H], er_sh[H];
  __shared__ float a_sh[CH * H];
  __shared__ int   src_sh[CH];

  float acc0 = 0.f, acc1 = 0.f;

  if (deg > 0) {
    // Phase A: online softmax stats per head (leader thread per head)
    if (tid < H) {
      float ern = er[(size_t)n * H + tid];
      er_sh[tid] = ern;
      float m = -3.0e38f, den = 0.f;
      for (int k = s; k < e_end; ++k) {
        int si = src[k];
        float v = el[(size_t)si * H + tid] + ern;
        v = (v > 0.f) ? v : 0.2f * v;                  // leaky_relu 0.2
        float mn = (v > m) ? v : m;
        den = den * __expf(m - mn) + __expf(v - mn);
        m = mn;
      }
      m_sh[tid] = m;
      inv_sh[tid] = 1.f / den;
    }
    __syncthreads();

    // Phase B: chunked alpha recompute + coalesced f32 z-row accumulation
    const int h = c0 / F;
    for (int k0 = s; k0 < e_end; k0 += CH) {
      const int kc = min(CH, e_end - k0);
      if (k0 > s) __syncthreads();
      for (int q = tid; q < kc * H; q += NT) {
        int kk = q / H, hh = q - kk * H;
        int si = src[k0 + kk];
        if (hh == 0) src_sh[kk] = si;
        float v = el[(size_t)si * H + hh] + er_sh[hh];
        v = (v > 0.f) ? v : 0.2f * v;
        a_sh[q] = __expf(v - m_sh[hh]) * inv_sh[hh];
      }
      __syncthreads();
      if (active) {
        for (int kk = 0; kk < kc; ++kk) {
          int si = src_sh[kk];
          float2 zz = *(const float2*)(z + (size_t)si * FH + c0);  // 8B/lane coalesced
          float aw = a_sh[kk * H + h];
          acc0 += aw * zz.x;
          acc1 += aw * zz.y;
        }
      }
    }
  }

  if (active) {
    if (ELU) {
      acc0 = (acc0 > 0.f) ? acc0 : (__expf(acc0) - 1.f);
      acc1 = (acc1 > 0.f) ? acc1 : (__expf(acc1) - 1.f);
    }
    if (SPLIT_OUT) {
      u16 h0 = f2bf(acc0), h1 = f2bf(acc1);
      u16 l0 = f2bf(acc0 - bf2f(h0)), l1 = f2bf(acc1 - bf2f(h1));
      u32 hi01 = ((u32)h1 << 16) | h0;
      u32 lo01 = ((u32)l1 << 16) | l0;
      u16* row = a2out + (size_t)n * (3 * FH);
      *(u32*)(row + c0) = hi01;
      *(u32*)(row + FH + c0) = hi01;
      *(u32*)(row + 2 * FH + c0) = lo01;
    } else {
      *(float2*)(fout + (size_t)n * FH + c0) = (float2){acc0, acc1};
    }
  }
}

extern "C" void kernel_launch(void* const* d_in, const int* in_sizes, int n_in,
                              void* d_out, int out_size, void* d_ws, size_t ws_size,
                              hipStream_t stream)
{
  constexpr int N = 25000, E = 400000, K1 = 256, HF = 512, CLS = 32;
  const float* h   = (const float*)d_in[0];
  const int*   src = (const int*)d_in[1];
  const int*   dst = (const int*)d_in[2];
  const float* W1  = (const float*)d_in[3];
  const float* al1 = (const float*)d_in[4];
  const float* ar1 = (const float*)d_in[5];
  const float* W2  = (const float*)d_in[6];
  const float* al2 = (const float*)d_in[7];
  const float* ar2 = (const float*)d_in[8];
  const float* W3  = (const float*)d_in[9];
  const float* al3 = (const float*)d_in[10];
  const float* ar3 = (const float*)d_in[11];
  float* out = (float*)d_out;

  // workspace carve-out (~131 MB)
  char* w = (char*)d_ws;
  auto take = [&](size_t bytes) {
    char* p = w;
    w += (bytes + 255) & ~(size_t)255;
    return p;
  };
  int*   rs = (int*)  take((size_t)(N + 1) * sizeof(int));
  float* el = (float*)take((size_t)N * 8 * sizeof(float));
  float* er = (float*)take((size_t)N * 8 * sizeof(float));
  float* z  = (float*)take((size_t)N * HF * sizeof(float));          // 51.2 MB
  u16*   A2 = (u16*)  take((size_t)N * 3 * HF * sizeof(u16));        // 76.8 MB
  u16*   B2 = (u16*)  take((size_t)HF * 3 * HF * sizeof(u16));       // 1.6 MB

  rowstart_kernel<<<dim3((N + 1 + 255) / 256), 256, 0, stream>>>(dst, rs, N, E);

  const dim3 gemmGrid(HF / 64, (N + 127) / 128);

  // ---- Layer 1: K=256 (K'=768), out 8x64 ----
  split_kernel<true ><<<dim3((N * K1 + 255) / 256), 256, 0, stream>>>(h,  A2, N * K1, K1);
  split_kernel<false><<<dim3((HF * K1 + 255) / 256), 256, 0, stream>>>(W1, B2, HF * K1, K1);
  gemm_bt_kernel<64><<<gemmGrid, 256, 0, stream>>>(A2, B2, z, N, HF, 3 * K1);
  elr_kernel<8, 64><<<dim3((N * 8 + 255) / 256), 256, 0, stream>>>(z, al1, ar1, el, er, N);
  agg_kernel<8, 64, 256, true, true><<<dim3(N), 256, 0, stream>>>(z, el, er, src, rs, nullptr, A2);

  // ---- Layer 2: K=512 (K'=1536), out 8x64 ----
  split_kernel<false><<<dim3((HF * HF + 255) / 256), 256, 0, stream>>>(W2, B2, HF * HF, HF);
  gemm_bt_kernel<64><<<gemmGrid, 256, 0, stream>>>(A2, B2, z, N, HF, 3 * HF);
  elr_kernel<8, 64><<<dim3((N * 8 + 255) / 256), 256, 0, stream>>>(z, al2, ar2, el, er, N);
  agg_kernel<8, 64, 256, true, true><<<dim3(N), 256, 0, stream>>>(z, el, er, src, rs, nullptr, A2);

  // ---- Layer 3: K=512 (K'=1536), out 1x32, no ELU, f32 to d_out ----
  split_kernel<false><<<dim3((CLS * HF + 255) / 256), 256, 0, stream>>>(W3, B2, CLS * HF, HF);
  gemm_bt_kernel<32><<<dim3(1, (N + 127) / 128), 256, 0, stream>>>(A2, B2, z, N, CLS, 3 * HF);
  elr_kernel<1, 32><<<dim3((N + 255) / 256), 256, 0, stream>>>(z, al3, ar3, el, er, N);
  agg_kernel<1, 32, 64, false, false><<<dim3(N), 64, 0, stream>>>(z, el, er, src, rs, out, nullptr);
}

// Round 3
// 637.214 us; speedup vs baseline: 1.0963x; 1.0963x over previous
//
#include <hip/hip_runtime.h>
#include <cstdint>

#define DEVINL __device__ __forceinline__

typedef uint16_t u16;
typedef uint32_t u32;
typedef uint64_t u64;
typedef __attribute__((ext_vector_type(8))) short short8;
typedef __attribute__((ext_vector_type(4))) float floatx4;
typedef const __attribute__((address_space(1))) void* gas_ptr;
typedef __attribute__((address_space(3))) void* las_ptr;

DEVINL u16 f2bf(float f) {
  u32 u = __float_as_uint(f);
  u32 r = u + 0x7FFFu + ((u >> 16) & 1u);   // RNE
  return (u16)(r >> 16);
}
DEVINL float bf2f(u16 b) { return __uint_as_float((u32)b << 16); }

// ---------- row_start[n] = lower_bound(dst, n) over sorted dst ----------
__global__ void rowstart_kernel(const int* __restrict__ dst, int* __restrict__ rs,
                                int N, int E) {
  int n = blockIdx.x * blockDim.x + threadIdx.x;
  if (n > N) return;
  int lo = 0, hi = E;
  while (lo < hi) { int mid = (lo + hi) >> 1; if (dst[mid] < n) lo = mid + 1; else hi = mid; }
  rs[n] = lo;
}

// ---------- f32 -> split-bf16 planar: A'=[hi|hi|lo], B'=[hi|lo|hi], row len 3K ----------
template<bool IsA>
__global__ __launch_bounds__(256)
void split_kernel(const float* __restrict__ in, u16* __restrict__ out, int MK, int K) {
  int idx = blockIdx.x * blockDim.x + threadIdx.x;
  if (idx >= MK) return;
  int m = idx / K, k = idx - m * K;
  float a = in[idx];
  u16 h = f2bf(a);
  u16 lo = f2bf(a - bf2f(h));
  size_t base = (size_t)m * 3 * K;
  if (IsA) { out[base + k] = h;  out[base + K + k] = h;  out[base + 2 * K + k] = lo; }
  else     { out[base + k] = h;  out[base + K + k] = lo; out[base + 2 * K + k] = h;  }
}

// ---------- GEMM: C[M,Nout](f32) = A'[M,K'] * B'[Nout,K']^T  (split-bf16 in) ----------
template<int BN>
__global__ __launch_bounds__(256)
void gemm_bt_kernel(const u16* __restrict__ A, const u16* __restrict__ B,
                    float* __restrict__ C, int M, int Nout, int K)
{
  constexpr int BM = 128, BK = 32;
  __shared__ __align__(16) u16 As[BM * BK];
  __shared__ __align__(16) u16 Bs[BN * BK];
  const int tid  = threadIdx.x;
  const int wave = tid >> 6;
  const int lane = tid & 63;
  const int quad = lane >> 4;
  const int l16  = lane & 15;
  const int rowBase = blockIdx.y * BM;
  const int colBase = blockIdx.x * BN;

  floatx4 acc[2][BN / 16];
  #pragma unroll
  for (int r = 0; r < 2; ++r)
    #pragma unroll
    for (int c = 0; c < BN / 16; ++c)
      acc[r][c] = (floatx4){0.f, 0.f, 0.f, 0.f};

  int aRow[2], aCol[2];
  #pragma unroll
  for (int i = 0; i < 2; ++i) {
    int flat = (2 * wave + i) * 512 + lane * 8;
    int r = flat >> 5;
    aCol[i] = flat & 31;
    int gr = rowBase + r;
    if (gr >= M) gr = M - 1;
    aRow[i] = gr;
  }
  constexpr int BCALLS = (BN * BK) / 512;
  int bRow = 0, bCol = 0;
  if (wave < BCALLS) {
    int flat = wave * 512 + lane * 8;
    bRow = colBase + (flat >> 5);
    bCol = flat & 31;
  }

  for (int k0 = 0; k0 < K; k0 += BK) {
    __syncthreads();
    #pragma unroll
    for (int i = 0; i < 2; ++i) {
      const u16* gp = A + (size_t)aRow[i] * K + (k0 + aCol[i]);
      __builtin_amdgcn_global_load_lds((gas_ptr)gp,
          (las_ptr)(As + (2 * wave + i) * 512), 16, 0, 0);
    }
    if (wave < BCALLS) {
      const u16* gp = B + (size_t)bRow * K + (k0 + bCol);
      __builtin_amdgcn_global_load_lds((gas_ptr)gp,
          (las_ptr)(Bs + wave * 512), 16, 0, 0);
    }
    __syncthreads();
    short8 a0 = *(const short8*)(As + (32 * wave + l16) * BK + quad * 8);
    short8 a1 = *(const short8*)(As + (32 * wave + 16 + l16) * BK + quad * 8);
    #pragma unroll
    for (int c = 0; c < BN / 16; ++c) {
      short8 b = *(const short8*)(Bs + (16 * c + l16) * BK + quad * 8);
      acc[0][c] = __builtin_amdgcn_mfma_f32_16x16x32_bf16(a0, b, acc[0][c], 0, 0, 0);
      acc[1][c] = __builtin_amdgcn_mfma_f32_16x16x32_bf16(a1, b, acc[1][c], 0, 0, 0);
    }
  }

  #pragma unroll
  for (int rt = 0; rt < 2; ++rt)
    #pragma unroll
    for (int c = 0; c < BN / 16; ++c)
      #pragma unroll
      for (int i = 0; i < 4; ++i) {
        int gr = rowBase + 32 * wave + 16 * rt + quad * 4 + i;
        if (gr < M) {
          int gc = colBase + 16 * c + l16;
          C[(size_t)gr * Nout + gc] = acc[rt][c][i];
        }
      }
}

// ---------- el[n,h] = sum_f z[n,h,f]*al[h,f]; er likewise (all f32) ----------
template<int H, int F>
__global__ __launch_bounds__(256)
void elr_kernel(const float* __restrict__ z, const float* __restrict__ al,
                const float* __restrict__ ar, float* __restrict__ el,
                float* __restrict__ er, int N)
{
  int t = blockIdx.x * blockDim.x + threadIdx.x;
  if (t >= N * H) return;
  int h = t % H;
  const float4* zp  = (const float4*)(z + (size_t)t * F);
  const float4* alp = (const float4*)(al + h * F);
  const float4* arp = (const float4*)(ar + h * F);
  float sl = 0.f, sr = 0.f;
  #pragma unroll
  for (int i = 0; i < F / 4; ++i) {
    float4 zz = zp[i], aa = alp[i], rr = arp[i];
    sl += zz.x * aa.x + zz.y * aa.y + zz.z * aa.z + zz.w * aa.w;
    sr += zz.x * rr.x + zz.y * rr.y + zz.z * rr.z + zz.w * rr.w;
  }
  el[t] = sl;
  er[t] = sr;
}

// ---------- single-pass softmax-aggregate (no max subtraction: shift-invariant) ----------
// out[n,:] = sum_e exp(v_e) z[src_e,:] / sum_e exp(v_e),  v_e = leaky_relu(el+er)
// One block per node. VC cols/thread. No LDS, no syncthreads: src/el loads are
// uniform-address broadcasts; CH-unrolled chunk keeps ~16 independent load chains in flight.
template<int H, int F, int NT, int VC, bool ELU, bool SPLIT_OUT>
__global__ __launch_bounds__(NT)
void agg_kernel(const float* __restrict__ z, const float* __restrict__ el,
                const float* __restrict__ er, const int* __restrict__ src,
                const int* __restrict__ rs, float* __restrict__ fout,
                u16* __restrict__ a2out)
{
  constexpr int FH = F * H;
  constexpr int GT = FH / VC;            // gather threads
  constexpr int CH = 16;                 // unrolled edge chunk
  const int n = blockIdx.x;
  const int tid = threadIdx.x;
  const int s = rs[n], e_end = rs[n + 1];
  const bool active = (tid < GT);
  const int c0 = VC * tid;
  const int h = active ? (c0 / F) : 0;

  float acc[VC];
  #pragma unroll
  for (int j = 0; j < VC; ++j) acc[j] = 0.f;
  float den = 0.f;
  const float er_h = er[(size_t)n * H + h];

  if (active) {
    for (int k0 = s; k0 < e_end; k0 += CH) {
      const int kc = min(CH, e_end - k0);
      #pragma unroll
      for (int kk = 0; kk < CH; ++kk) {
        if (kk < kc) {                                   // wave-uniform guard
          int si = src[k0 + kk];                         // broadcast load
          float v = el[(size_t)si * H + h] + er_h;       // broadcast load
          v = (v > 0.f) ? v : 0.2f * v;                  // leaky_relu 0.2
          float wgt = __expf(v);
          const float* zp = z + (size_t)si * FH + c0;    // coalesced row gather
          if constexpr (VC == 4) {
            float4 z4 = *(const float4*)zp;
            acc[0] += wgt * z4.x; acc[1] += wgt * z4.y;
            acc[2] += wgt * z4.z; acc[3] += wgt * z4.w;
          } else {
            #pragma unroll
            for (int j = 0; j < VC; ++j) acc[j] += wgt * zp[j];
          }
          den += wgt;
        }
      }
    }
  }

  if (active) {
    float o[VC];
    const float r = (e_end > s) ? (1.f / den) : 0.f;     // deg==0 -> zeros
    #pragma unroll
    for (int j = 0; j < VC; ++j) {
      float v = acc[j] * r;
      if (ELU) v = (v > 0.f) ? v : (__expf(v) - 1.f);
      o[j] = v;
    }
    if constexpr (SPLIT_OUT) {
      u64 hp = 0, lp = 0;
      #pragma unroll
      for (int j = 0; j < VC; ++j) {
        u16 hi = f2bf(o[j]);
        u16 lo = f2bf(o[j] - bf2f(hi));
        hp |= (u64)hi << (16 * j);
        lp |= (u64)lo << (16 * j);
      }
      u16* row = a2out + (size_t)n * (3 * FH);
      *(u64*)(row + c0) = hp;
      *(u64*)(row + FH + c0) = hp;
      *(u64*)(row + 2 * FH + c0) = lp;
    } else {
      float* op = fout + (size_t)n * FH + c0;
      #pragma unroll
      for (int j = 0; j < VC; ++j) op[j] = o[j];
    }
  }
}

extern "C" void kernel_launch(void* const* d_in, const int* in_sizes, int n_in,
                              void* d_out, int out_size, void* d_ws, size_t ws_size,
                              hipStream_t stream)
{
  constexpr int N = 25000, E = 400000, K1 = 256, HF = 512, CLS = 32;
  const float* h   = (const float*)d_in[0];
  const int*   src = (const int*)d_in[1];
  const int*   dst = (const int*)d_in[2];
  const float* W1  = (const float*)d_in[3];
  const float* al1 = (const float*)d_in[4];
  const float* ar1 = (const float*)d_in[5];
  const float* W2  = (const float*)d_in[6];
  const float* al2 = (const float*)d_in[7];
  const float* ar2 = (const float*)d_in[8];
  const float* W3  = (const float*)d_in[9];
  const float* al3 = (const float*)d_in[10];
  const float* ar3 = (const float*)d_in[11];
  float* out = (float*)d_out;

  char* w = (char*)d_ws;
  auto take = [&](size_t bytes) {
    char* p = w;
    w += (bytes + 255) & ~(size_t)255;
    return p;
  };
  int*   rs = (int*)  take((size_t)(N + 1) * sizeof(int));
  float* el = (float*)take((size_t)N * 8 * sizeof(float));
  float* er = (float*)take((size_t)N * 8 * sizeof(float));
  float* z  = (float*)take((size_t)N * HF * sizeof(float));          // 51.2 MB
  u16*   A2 = (u16*)  take((size_t)N * 3 * HF * sizeof(u16));        // 76.8 MB
  u16*   B2 = (u16*)  take((size_t)HF * 3 * HF * sizeof(u16));       // 1.6 MB

  rowstart_kernel<<<dim3((N + 1 + 255) / 256), 256, 0, stream>>>(dst, rs, N, E);

  const dim3 gemmGrid(HF / 64, (N + 127) / 128);

  // ---- Layer 1: K=256 (K'=768), out 8x64 ----
  split_kernel<true ><<<dim3((N * K1 + 255) / 256), 256, 0, stream>>>(h,  A2, N * K1, K1);
  split_kernel<false><<<dim3((HF * K1 + 255) / 256), 256, 0, stream>>>(W1, B2, HF * K1, K1);
  gemm_bt_kernel<64><<<gemmGrid, 256, 0, stream>>>(A2, B2, z, N, HF, 3 * K1);
  elr_kernel<8, 64><<<dim3((N * 8 + 255) / 256), 256, 0, stream>>>(z, al1, ar1, el, er, N);
  agg_kernel<8, 64, 128, 4, true, true><<<dim3(N), 128, 0, stream>>>(z, el, er, src, rs, nullptr, A2);

  // ---- Layer 2: K=512 (K'=1536), out 8x64 ----
  split_kernel<false><<<dim3((HF * HF + 255) / 256), 256, 0, stream>>>(W2, B2, HF * HF, HF);
  gemm_bt_kernel<64><<<gemmGrid, 256, 0, stream>>>(A2, B2, z, N, HF, 3 * HF);
  elr_kernel<8, 64><<<dim3((N * 8 + 255) / 256), 256, 0, stream>>>(z, al2, ar2, el, er, N);
  agg_kernel<8, 64, 128, 4, true, true><<<dim3(N), 128, 0, stream>>>(z, el, er, src, rs, nullptr, A2);

  // ---- Layer 3: K=512 (K'=1536), out 1x32, no ELU, f32 to d_out ----
  split_kernel<false><<<dim3((CLS * HF + 255) / 256), 256, 0, stream>>>(W3, B2, CLS * HF, HF);
  gemm_bt_kernel<32><<<dim3(1, (N + 127) / 128), 256, 0, stream>>>(A2, B2, z, N, CLS, 3 * HF);
  elr_kernel<1, 32><<<dim3((N + 255) / 256), 256, 0, stream>>>(z, al3, ar3, el, er, N);
  agg_kernel<1, 32, 64, 1, false, false><<<dim3(N), 64, 0, stream>>>(z, el, er, src, rs, out, nullptr);
}

// Round 4
// 483.529 us; speedup vs baseline: 1.4448x; 1.3178x over previous
//
#include <hip/hip_runtime.h>
#include <cstdint>

#define DEVINL __device__ __forceinline__

typedef uint16_t u16;
typedef uint32_t u32;
typedef uint64_t u64;
typedef __attribute__((ext_vector_type(8))) short short8;
typedef __attribute__((ext_vector_type(4))) float floatx4;
typedef __attribute__((ext_vector_type(4))) u32 u32x4;
typedef const __attribute__((address_space(1))) void* gas_ptr;
typedef __attribute__((address_space(3))) void* las_ptr;

DEVINL u16 f2bf(float f) {
  u32 u = __float_as_uint(f);
  u32 r = u + 0x7FFFu + ((u >> 16) & 1u);   // RNE
  return (u16)(r >> 16);
}
DEVINL float bf2f(u16 b) { return __uint_as_float((u32)b << 16); }
DEVINL float bf_lo(u32 u) { return __uint_as_float(u << 16); }
DEVINL float bf_hi(u32 u) { return __uint_as_float(u & 0xFFFF0000u); }

// ---------- row_start[n] = lower_bound(dst, n) over sorted dst ----------
__global__ void rowstart_kernel(const int* __restrict__ dst, int* __restrict__ rs,
                                int N, int E) {
  int n = blockIdx.x * blockDim.x + threadIdx.x;
  if (n > N) return;
  int lo = 0, hi = E;
  while (lo < hi) { int mid = (lo + hi) >> 1; if (dst[mid] < n) lo = mid + 1; else hi = mid; }
  rs[n] = lo;
}

__global__ void zero_kernel(float* __restrict__ p, int n) {
  int i = blockIdx.x * blockDim.x + threadIdx.x;
  if (i < n) p[i] = 0.f;
}

// ---------- f32 -> split-bf16 planar: A'=[hi|hi|lo], B'=[hi|lo|hi], row len 3K ----------
template<bool IsA>
__global__ __launch_bounds__(256)
void split_kernel(const float* __restrict__ in, u16* __restrict__ out, int MK, int K) {
  int idx = blockIdx.x * blockDim.x + threadIdx.x;
  if (idx >= MK) return;
  int m = idx / K, k = idx - m * K;
  float a = in[idx];
  u16 h = f2bf(a);
  u16 lo = f2bf(a - bf2f(h));
  size_t base = (size_t)m * 3 * K;
  if (IsA) { out[base + k] = h;  out[base + K + k] = h;  out[base + 2 * K + k] = lo; }
  else     { out[base + k] = h;  out[base + K + k] = lo; out[base + 2 * K + k] = h;  }
}

// ---------- GEMM: C[M,Nout] = A'[M,K'] * B'[Nout,K']^T  (split-bf16 in) ----------
// BM=128, BK=32, 256 threads (4 waves); wave w owns rows [32w,32w+32).
// OUTM: 1 = bf16 store, 2 = f32 atomicAdd (split-K: blockIdx.x indexes K-chunk).
template<int BN, int OUTM>
__global__ __launch_bounds__(256)
void gemm_bt_kernel(const u16* __restrict__ A, const u16* __restrict__ B,
                    float* __restrict__ Cf, u16* __restrict__ Cb,
                    int M, int Nout, int K, int kLen)
{
  constexpr int BM = 128, BK = 32, CF = BN / 16;
  constexpr int BCALLS = (BN * BK) / 512;          // 8 for BN=128, 2 for BN=32
  __shared__ __align__(16) u16 As[BM * BK];
  __shared__ __align__(16) u16 Bs[BN * BK];
  const int tid  = threadIdx.x;
  const int wave = tid >> 6;
  const int lane = tid & 63;
  const int quad = lane >> 4;
  const int l16  = lane & 15;
  const int rowBase = blockIdx.y * BM;
  const int colBase = (OUTM == 2) ? 0 : blockIdx.x * BN;
  const int kStart  = (OUTM == 2) ? blockIdx.x * kLen : 0;

  floatx4 acc[2][CF];
  #pragma unroll
  for (int r = 0; r < 2; ++r)
    #pragma unroll
    for (int c = 0; c < CF; ++c)
      acc[r][c] = (floatx4){0.f, 0.f, 0.f, 0.f};

  // A staging: 8 wave-calls; wave w does calls {w, w+4}.
  int aRow[2], aCol[2];
  #pragma unroll
  for (int i = 0; i < 2; ++i) {
    int call = wave + 4 * i;
    int flat = call * 512 + lane * 8;              // elem idx in 128x32 tile
    int r = flat >> 5;
    aCol[i] = flat & 31;
    int gr = rowBase + r;
    if (gr >= M) gr = M - 1;                       // clamp: safe load, store guarded
    aRow[i] = gr;
  }
  // B staging: BCALLS wave-calls; wave w does {w, w+4} below BCALLS.
  int bRow[2] = {0, 0}, bCol[2] = {0, 0};
  #pragma unroll
  for (int i = 0; i < 2; ++i) {
    int call = wave + 4 * i;
    if (call < BCALLS) {
      int flat = call * 512 + lane * 8;
      bRow[i] = colBase + (flat >> 5);
      bCol[i] = flat & 31;
    }
  }

  for (int k0 = kStart; k0 < kStart + kLen; k0 += BK) {
    __syncthreads();
    #pragma unroll
    for (int i = 0; i < 2; ++i) {
      int call = wave + 4 * i;
      const u16* gp = A + (size_t)aRow[i] * K + (k0 + aCol[i]);
      __builtin_amdgcn_global_load_lds((gas_ptr)gp,
          (las_ptr)(As + call * 512), 16, 0, 0);
    }
    #pragma unroll
    for (int i = 0; i < 2; ++i) {
      int call = wave + 4 * i;
      if (call < BCALLS) {
        const u16* gp = B + (size_t)bRow[i] * K + (k0 + bCol[i]);
        __builtin_amdgcn_global_load_lds((gas_ptr)gp,
            (las_ptr)(Bs + call * 512), 16, 0, 0);
      }
    }
    __syncthreads();
    short8 a0 = *(const short8*)(As + (32 * wave + l16) * BK + quad * 8);
    short8 a1 = *(const short8*)(As + (32 * wave + 16 + l16) * BK + quad * 8);
    #pragma unroll
    for (int c = 0; c < CF; ++c) {
      short8 b = *(const short8*)(Bs + (16 * c + l16) * BK + quad * 8);
      acc[0][c] = __builtin_amdgcn_mfma_f32_16x16x32_bf16(a0, b, acc[0][c], 0, 0, 0);
      acc[1][c] = __builtin_amdgcn_mfma_f32_16x16x32_bf16(a1, b, acc[1][c], 0, 0, 0);
    }
  }

  // C/D layout: col = lane&15, row = quad*4 + reg (verified m89/m91)
  #pragma unroll
  for (int rt = 0; rt < 2; ++rt)
    #pragma unroll
    for (int c = 0; c < CF; ++c)
      #pragma unroll
      for (int i = 0; i < 4; ++i) {
        int gr = rowBase + 32 * wave + 16 * rt + quad * 4 + i;
        if (gr < M) {
          int gc = colBase + 16 * c + l16;
          if (OUTM == 1) Cb[(size_t)gr * Nout + gc] = f2bf(acc[rt][c][i]);
          else           atomicAdd(Cf + (size_t)gr * Nout + gc, acc[rt][c][i]);
        }
      }
}

// ---------- el/er from bf16 z (H=8, F=64) ----------
__global__ __launch_bounds__(256)
void elr_bf16_kernel(const u16* __restrict__ z, const float* __restrict__ al,
                     const float* __restrict__ ar, float* __restrict__ el,
                     float* __restrict__ er, int N)
{
  int t = blockIdx.x * blockDim.x + threadIdx.x;
  if (t >= N * 8) return;
  int h = t & 7;
  const u32x4* zp = (const u32x4*)(z + (size_t)t * 64);
  const float* alp = al + h * 64;
  const float* arp = ar + h * 64;
  float sl = 0.f, sr = 0.f;
  #pragma unroll
  for (int i = 0; i < 8; ++i) {
    u32x4 zz = zp[i];
    #pragma unroll
    for (int j = 0; j < 4; ++j) {
      float z0 = bf_lo(zz[j]), z1 = bf_hi(zz[j]);
      int f = i * 8 + 2 * j;
      sl += z0 * alp[f] + z1 * alp[f + 1];
      sr += z0 * arp[f] + z1 * arp[f + 1];
    }
  }
  el[t] = sl;
  er[t] = sr;
}

// ---------- f32 elr (layer 3, H=1, F=32) ----------
template<int H, int F>
__global__ __launch_bounds__(256)
void elr_kernel(const float* __restrict__ z, const float* __restrict__ al,
                const float* __restrict__ ar, float* __restrict__ el,
                float* __restrict__ er, int N)
{
  int t = blockIdx.x * blockDim.x + threadIdx.x;
  if (t >= N * H) return;
  int h = t % H;
  const float4* zp  = (const float4*)(z + (size_t)t * F);
  const float4* alp = (const float4*)(al + h * F);
  const float4* arp = (const float4*)(ar + h * F);
  float sl = 0.f, sr = 0.f;
  #pragma unroll
  for (int i = 0; i < F / 4; ++i) {
    float4 zz = zp[i], aa = alp[i], rr = arp[i];
    sl += zz.x * aa.x + zz.y * aa.y + zz.z * aa.z + zz.w * aa.w;
    sr += zz.x * rr.x + zz.y * rr.y + zz.z * rr.z + zz.w * rr.w;
  }
  el[t] = sl;
  er[t] = sr;
}

// ---------- layers 1/2 aggregate: bf16 z gather, 1 wave/node, 8 cols/thread ----------
// out = sum_e exp(v_e) z[src_e] / sum_e exp(v_e)  (shift-invariant softmax, no max pass)
__global__ __launch_bounds__(64)
void agg_bf16_kernel(const u16* __restrict__ z, const float* __restrict__ el,
                     const float* __restrict__ er, const int* __restrict__ src,
                     const int* __restrict__ rs, u16* __restrict__ a2out)
{
  const int n = blockIdx.x, tid = threadIdx.x;
  const int s = rs[n], e = rs[n + 1];
  const int c0 = tid * 8;                          // 8 bf16 cols = 16 B/lane
  const int h = tid >> 3;                          // c0 / 64
  const float er_h = er[(size_t)n * 8 + h];

  float acc[8];
  #pragma unroll
  for (int j = 0; j < 8; ++j) acc[j] = 0.f;
  float den = 0.f;

  for (int k0 = s; k0 < e; k0 += 8) {
    const int kc = e - k0;
    #pragma unroll
    for (int kk = 0; kk < 8; ++kk) {
      if (kk < kc) {                               // wave-uniform guard
        int si = src[k0 + kk];                     // broadcast load
        float v = el[(size_t)si * 8 + h] + er_h;   // broadcast load
        v = (v > 0.f) ? v : 0.2f * v;              // leaky_relu 0.2
        float wgt = __expf(v);
        u32x4 zz = *(const u32x4*)(z + (size_t)si * 512 + c0);  // 16B/lane coalesced
        #pragma unroll
        for (int j = 0; j < 4; ++j) {
          acc[2 * j]     += wgt * bf_lo(zz[j]);
          acc[2 * j + 1] += wgt * bf_hi(zz[j]);
        }
        den += wgt;
      }
    }
  }

  const float r = (e > s) ? (1.f / den) : 0.f;     // deg==0 -> zeros (elu(0)=0)
  u32x4 hp, lp;
  #pragma unroll
  for (int j = 0; j < 4; ++j) {
    float o0 = acc[2 * j] * r, o1 = acc[2 * j + 1] * r;
    o0 = (o0 > 0.f) ? o0 : (__expf(o0) - 1.f);     // elu
    o1 = (o1 > 0.f) ? o1 : (__expf(o1) - 1.f);
    u16 h0 = f2bf(o0), h1 = f2bf(o1);
    u16 l0 = f2bf(o0 - bf2f(h0)), l1 = f2bf(o1 - bf2f(h1));
    hp[j] = ((u32)h1 << 16) | h0;
    lp[j] = ((u32)l1 << 16) | l0;
  }
  u16* row = a2out + (size_t)n * 1536;             // A' = [hi|hi|lo]
  *(u32x4*)(row + c0) = hp;
  *(u32x4*)(row + 512 + c0) = hp;
  *(u32x4*)(row + 1024 + c0) = lp;
}

// ---------- layer 3 aggregate: f32 z3 (3.2 MB, L2-resident), 32 cols ----------
__global__ __launch_bounds__(64)
void agg3_kernel(const float* __restrict__ z, const float* __restrict__ el,
                 const float* __restrict__ er, const int* __restrict__ src,
                 const int* __restrict__ rs, float* __restrict__ out)
{
  const int n = blockIdx.x, tid = threadIdx.x;
  const int s = rs[n], e = rs[n + 1];
  const bool active = (tid < 32);
  const float er_n = er[n];
  float acc = 0.f, den = 0.f;

  for (int k0 = s; k0 < e; k0 += 8) {
    const int kc = e - k0;
    #pragma unroll
    for (int kk = 0; kk < 8; ++kk) {
      if (kk < kc) {
        int si = src[k0 + kk];
        float v = el[si] + er_n;
        v = (v > 0.f) ? v : 0.2f * v;
        float wgt = __expf(v);
        if (active) acc += wgt * z[(size_t)si * 32 + tid];
        den += wgt;
      }
    }
  }
  if (active) out[(size_t)n * 32 + tid] = (e > s) ? (acc / den) : 0.f;
}

extern "C" void kernel_launch(void* const* d_in, const int* in_sizes, int n_in,
                              void* d_out, int out_size, void* d_ws, size_t ws_size,
                              hipStream_t stream)
{
  constexpr int N = 25000, E = 400000, K1 = 256, HF = 512, CLS = 32;
  const float* h   = (const float*)d_in[0];
  const int*   src = (const int*)d_in[1];
  const int*   dst = (const int*)d_in[2];
  const float* W1  = (const float*)d_in[3];
  const float* al1 = (const float*)d_in[4];
  const float* ar1 = (const float*)d_in[5];
  const float* W2  = (const float*)d_in[6];
  const float* al2 = (const float*)d_in[7];
  const float* ar2 = (const float*)d_in[8];
  const float* W3  = (const float*)d_in[9];
  const float* al3 = (const float*)d_in[10];
  const float* ar3 = (const float*)d_in[11];
  float* out = (float*)d_out;

  char* w = (char*)d_ws;
  auto take = [&](size_t bytes) {
    char* p = w;
    w += (bytes + 255) & ~(size_t)255;
    return p;
  };
  int*   rs = (int*)  take((size_t)(N + 1) * sizeof(int));
  float* el = (float*)take((size_t)N * 8 * sizeof(float));
  float* er = (float*)take((size_t)N * 8 * sizeof(float));
  float* z3 = (float*)take((size_t)N * CLS * sizeof(float));         // 3.2 MB
  u16*   zb = (u16*)  take((size_t)N * HF * sizeof(u16));            // 25.6 MB
  u16*   A2 = (u16*)  take((size_t)N * 3 * HF * sizeof(u16));        // 76.8 MB
  u16*   B2 = (u16*)  take((size_t)HF * 3 * HF * sizeof(u16));       // 1.6 MB

  rowstart_kernel<<<dim3((N + 1 + 255) / 256), 256, 0, stream>>>(dst, rs, N, E);

  const dim3 gemmGrid(HF / 128, (N + 127) / 128);   // 4 x 196

  // ---- Layer 1: K'=768 ----
  split_kernel<true ><<<dim3((N * K1 + 255) / 256), 256, 0, stream>>>(h,  A2, N * K1, K1);
  split_kernel<false><<<dim3((HF * K1 + 255) / 256), 256, 0, stream>>>(W1, B2, HF * K1, K1);
  gemm_bt_kernel<128, 1><<<gemmGrid, 256, 0, stream>>>(A2, B2, nullptr, zb, N, HF, 3 * K1, 3 * K1);
  elr_bf16_kernel<<<dim3((N * 8 + 255) / 256), 256, 0, stream>>>(zb, al1, ar1, el, er, N);
  agg_bf16_kernel<<<dim3(N), 64, 0, stream>>>(zb, el, er, src, rs, A2);

  // ---- Layer 2: K'=1536 ----
  split_kernel<false><<<dim3((HF * HF + 255) / 256), 256, 0, stream>>>(W2, B2, HF * HF, HF);
  gemm_bt_kernel<128, 1><<<gemmGrid, 256, 0, stream>>>(A2, B2, nullptr, zb, N, HF, 3 * HF, 3 * HF);
  elr_bf16_kernel<<<dim3((N * 8 + 255) / 256), 256, 0, stream>>>(zb, al2, ar2, el, er, N);
  agg_bf16_kernel<<<dim3(N), 64, 0, stream>>>(zb, el, er, src, rs, A2);

  // ---- Layer 3: K'=1536, Nout=32, split-K=4 + atomicAdd ----
  split_kernel<false><<<dim3((CLS * HF + 255) / 256), 256, 0, stream>>>(W3, B2, CLS * HF, HF);
  zero_kernel<<<dim3((N * CLS + 255) / 256), 256, 0, stream>>>(z3, N * CLS);
  gemm_bt_kernel<32, 2><<<dim3(4, (N + 127) / 128), 256, 0, stream>>>(A2, B2, z3, nullptr, N, CLS, 3 * HF, (3 * HF) / 4);
  elr_kernel<1, 32><<<dim3((N + 255) / 256), 256, 0, stream>>>(z3, al3, ar3, el, er, N);
  agg3_kernel<<<dim3(N), 64, 0, stream>>>(z3, el, er, src, rs, out);
}

// Round 5
// 429.683 us; speedup vs baseline: 1.6258x; 1.1253x over previous
//
#include <hip/hip_runtime.h>
#include <cstdint>

#define DEVINL __device__ __forceinline__

typedef uint16_t u16;
typedef uint32_t u32;
typedef uint64_t u64;
typedef __attribute__((ext_vector_type(8))) short short8;
typedef __attribute__((ext_vector_type(4))) float floatx4;
typedef __attribute__((ext_vector_type(4))) u32 u32x4;
typedef const __attribute__((address_space(1))) void* gas_ptr;
typedef __attribute__((address_space(3))) void* las_ptr;

DEVINL u16 f2bf(float f) {
  u32 u = __float_as_uint(f);
  u32 r = u + 0x7FFFu + ((u >> 16) & 1u);   // RNE
  return (u16)(r >> 16);
}
DEVINL float bf2f(u16 b) { return __uint_as_float((u32)b << 16); }
DEVINL float bf_lo(u32 u) { return __uint_as_float(u << 16); }
DEVINL float bf_hi(u32 u) { return __uint_as_float(u & 0xFFFF0000u); }

// ---------- row_start[n] = lower_bound(dst, n) over sorted dst ----------
__global__ void rowstart_kernel(const int* __restrict__ dst, int* __restrict__ rs,
                                int N, int E) {
  int n = blockIdx.x * blockDim.x + threadIdx.x;
  if (n > N) return;
  int lo = 0, hi = E;
  while (lo < hi) { int mid = (lo + hi) >> 1; if (dst[mid] < n) lo = mid + 1; else hi = mid; }
  rs[n] = lo;
}

__global__ void zero_kernel(float* __restrict__ p, int n) {
  int i = blockIdx.x * blockDim.x + threadIdx.x;
  if (i < n) p[i] = 0.f;
}

// ---------- f32 -> 2-plane split-bf16: A'=[hi|lo], B'=[hi|hi], row len 2K ----------
// A-side: exact split (hi+lo = a to f32 precision). B-side: weights bf16-quantized.
template<bool IsA>
__global__ __launch_bounds__(256)
void split_kernel(const float* __restrict__ in, u16* __restrict__ out, int MK, int K) {
  int idx = blockIdx.x * blockDim.x + threadIdx.x;
  if (idx >= MK) return;
  int m = idx / K, k = idx - m * K;
  float a = in[idx];
  u16 h = f2bf(a);
  size_t base = (size_t)m * 2 * K;
  if (IsA) {
    u16 lo = f2bf(a - bf2f(h));
    out[base + k] = h;  out[base + K + k] = lo;
  } else {
    out[base + k] = h;  out[base + K + k] = h;
  }
}

// ---------- GEMM: C[M,Nout] = A'[M,K'] * B'[Nout,K']^T  (split-bf16 in) ----------
// BM=128, BK=32, 256 threads (4 waves); wave w owns rows [32w,32w+32).
// OUTM: 1 = bf16 store, 2 = f32 atomicAdd (split-K: blockIdx.x indexes K-chunk).
template<int BN, int OUTM>
__global__ __launch_bounds__(256)
void gemm_bt_kernel(const u16* __restrict__ A, const u16* __restrict__ B,
                    float* __restrict__ Cf, u16* __restrict__ Cb,
                    int M, int Nout, int K, int kLen)
{
  constexpr int BM = 128, BK = 32, CF = BN / 16;
  constexpr int BCALLS = (BN * BK) / 512;          // 8 for BN=128, 2 for BN=32
  __shared__ __align__(16) u16 As[BM * BK];
  __shared__ __align__(16) u16 Bs[BN * BK];
  const int tid  = threadIdx.x;
  const int wave = tid >> 6;
  const int lane = tid & 63;
  const int quad = lane >> 4;
  const int l16  = lane & 15;
  const int rowBase = blockIdx.y * BM;
  const int colBase = (OUTM == 2) ? 0 : blockIdx.x * BN;
  const int kStart  = (OUTM == 2) ? blockIdx.x * kLen : 0;

  floatx4 acc[2][CF];
  #pragma unroll
  for (int r = 0; r < 2; ++r)
    #pragma unroll
    for (int c = 0; c < CF; ++c)
      acc[r][c] = (floatx4){0.f, 0.f, 0.f, 0.f};

  // A staging: 8 wave-calls; wave w does calls {w, w+4}.
  int aRow[2], aCol[2];
  #pragma unroll
  for (int i = 0; i < 2; ++i) {
    int call = wave + 4 * i;
    int flat = call * 512 + lane * 8;              // elem idx in 128x32 tile
    int r = flat >> 5;
    aCol[i] = flat & 31;
    int gr = rowBase + r;
    if (gr >= M) gr = M - 1;                       // clamp: safe load, store guarded
    aRow[i] = gr;
  }
  // B staging: BCALLS wave-calls; wave w does {w, w+4} below BCALLS.
  int bRow[2] = {0, 0}, bCol[2] = {0, 0};
  #pragma unroll
  for (int i = 0; i < 2; ++i) {
    int call = wave + 4 * i;
    if (call < BCALLS) {
      int flat = call * 512 + lane * 8;
      bRow[i] = colBase + (flat >> 5);
      bCol[i] = flat & 31;
    }
  }

  for (int k0 = kStart; k0 < kStart + kLen; k0 += BK) {
    __syncthreads();
    #pragma unroll
    for (int i = 0; i < 2; ++i) {
      int call = wave + 4 * i;
      const u16* gp = A + (size_t)aRow[i] * K + (k0 + aCol[i]);
      __builtin_amdgcn_global_load_lds((gas_ptr)gp,
          (las_ptr)(As + call * 512), 16, 0, 0);
    }
    #pragma unroll
    for (int i = 0; i < 2; ++i) {
      int call = wave + 4 * i;
      if (call < BCALLS) {
        const u16* gp = B + (size_t)bRow[i] * K + (k0 + bCol[i]);
        __builtin_amdgcn_global_load_lds((gas_ptr)gp,
            (las_ptr)(Bs + call * 512), 16, 0, 0);
      }
    }
    __syncthreads();
    short8 a0 = *(const short8*)(As + (32 * wave + l16) * BK + quad * 8);
    short8 a1 = *(const short8*)(As + (32 * wave + 16 + l16) * BK + quad * 8);
    #pragma unroll
    for (int c = 0; c < CF; ++c) {
      short8 b = *(const short8*)(Bs + (16 * c + l16) * BK + quad * 8);
      acc[0][c] = __builtin_amdgcn_mfma_f32_16x16x32_bf16(a0, b, acc[0][c], 0, 0, 0);
      acc[1][c] = __builtin_amdgcn_mfma_f32_16x16x32_bf16(a1, b, acc[1][c], 0, 0, 0);
    }
  }

  // C/D layout: col = lane&15, row = quad*4 + reg (verified m89/m91)
  #pragma unroll
  for (int rt = 0; rt < 2; ++rt)
    #pragma unroll
    for (int c = 0; c < CF; ++c)
      #pragma unroll
      for (int i = 0; i < 4; ++i) {
        int gr = rowBase + 32 * wave + 16 * rt + quad * 4 + i;
        if (gr < M) {
          int gc = colBase + 16 * c + l16;
          if (OUTM == 1) Cb[(size_t)gr * Nout + gc] = f2bf(acc[rt][c][i]);
          else           atomicAdd(Cf + (size_t)gr * Nout + gc, acc[rt][c][i]);
        }
      }
}

// ---------- el/er from bf16 z (H=8, F=64) ----------
__global__ __launch_bounds__(256)
void elr_bf16_kernel(const u16* __restrict__ z, const float* __restrict__ al,
                     const float* __restrict__ ar, float* __restrict__ el,
                     float* __restrict__ er, int N)
{
  int t = blockIdx.x * blockDim.x + threadIdx.x;
  if (t >= N * 8) return;
  int h = t & 7;
  const u32x4* zp = (const u32x4*)(z + (size_t)t * 64);
  const float* alp = al + h * 64;
  const float* arp = ar + h * 64;
  float sl = 0.f, sr = 0.f;
  #pragma unroll
  for (int i = 0; i < 8; ++i) {
    u32x4 zz = zp[i];
    #pragma unroll
    for (int j = 0; j < 4; ++j) {
      float z0 = bf_lo(zz[j]), z1 = bf_hi(zz[j]);
      int f = i * 8 + 2 * j;
      sl += z0 * alp[f] + z1 * alp[f + 1];
      sr += z0 * arp[f] + z1 * arp[f + 1];
    }
  }
  el[t] = sl;
  er[t] = sr;
}

// ---------- f32 elr (layer 3, H=1, F=32) ----------
template<int H, int F>
__global__ __launch_bounds__(256)
void elr_kernel(const float* __restrict__ z, const float* __restrict__ al,
                const float* __restrict__ ar, float* __restrict__ el,
                float* __restrict__ er, int N)
{
  int t = blockIdx.x * blockDim.x + threadIdx.x;
  if (t >= N * H) return;
  int h = t % H;
  const float4* zp  = (const float4*)(z + (size_t)t * F);
  const float4* alp = (const float4*)(al + h * F);
  const float4* arp = (const float4*)(ar + h * F);
  float sl = 0.f, sr = 0.f;
  #pragma unroll
  for (int i = 0; i < F / 4; ++i) {
    float4 zz = zp[i], aa = alp[i], rr = arp[i];
    sl += zz.x * aa.x + zz.y * aa.y + zz.z * aa.z + zz.w * aa.w;
    sr += zz.x * rr.x + zz.y * rr.y + zz.z * rr.z + zz.w * rr.w;
  }
  el[t] = sl;
  er[t] = sr;
}

// ---------- layers 1/2 aggregate: bf16 z gather, 1 wave/node, 8 cols/thread ----------
// out = sum_e exp(v_e) z[src_e] / sum_e exp(v_e)  (shift-invariant softmax, no max pass)
// Epilogue writes next layer's A' = [hi|lo] (row len 1024).
__global__ __launch_bounds__(64)
void agg_bf16_kernel(const u16* __restrict__ z, const float* __restrict__ el,
                     const float* __restrict__ er, const int* __restrict__ src,
                     const int* __restrict__ rs, u16* __restrict__ a2out)
{
  const int n = blockIdx.x, tid = threadIdx.x;
  const int s = rs[n], e = rs[n + 1];
  const int c0 = tid * 8;                          // 8 bf16 cols = 16 B/lane
  const int h = tid >> 3;                          // c0 / 64
  const float er_h = er[(size_t)n * 8 + h];

  float acc[8];
  #pragma unroll
  for (int j = 0; j < 8; ++j) acc[j] = 0.f;
  float den = 0.f;

  for (int k0 = s; k0 < e; k0 += 8) {
    const int kc = e - k0;
    #pragma unroll
    for (int kk = 0; kk < 8; ++kk) {
      if (kk < kc) {                               // wave-uniform guard
        int si = src[k0 + kk];                     // broadcast load
        float v = el[(size_t)si * 8 + h] + er_h;   // broadcast load
        v = (v > 0.f) ? v : 0.2f * v;              // leaky_relu 0.2
        float wgt = __expf(v);
        u32x4 zz = *(const u32x4*)(z + (size_t)si * 512 + c0);  // 16B/lane coalesced
        #pragma unroll
        for (int j = 0; j < 4; ++j) {
          acc[2 * j]     += wgt * bf_lo(zz[j]);
          acc[2 * j + 1] += wgt * bf_hi(zz[j]);
        }
        den += wgt;
      }
    }
  }

  const float r = (e > s) ? (1.f / den) : 0.f;     // deg==0 -> zeros (elu(0)=0)
  u32x4 hp, lp;
  #pragma unroll
  for (int j = 0; j < 4; ++j) {
    float o0 = acc[2 * j] * r, o1 = acc[2 * j + 1] * r;
    o0 = (o0 > 0.f) ? o0 : (__expf(o0) - 1.f);     // elu
    o1 = (o1 > 0.f) ? o1 : (__expf(o1) - 1.f);
    u16 h0 = f2bf(o0), h1 = f2bf(o1);
    u16 l0 = f2bf(o0 - bf2f(h0)), l1 = f2bf(o1 - bf2f(h1));
    hp[j] = ((u32)h1 << 16) | h0;
    lp[j] = ((u32)l1 << 16) | l0;
  }
  u16* row = a2out + (size_t)n * 1024;             // A' = [hi|lo]
  *(u32x4*)(row + c0) = hp;
  *(u32x4*)(row + 512 + c0) = lp;
}

// ---------- layer 3 aggregate: f32 z3 (3.2 MB, L2-resident), 32 cols ----------
__global__ __launch_bounds__(64)
void agg3_kernel(const float* __restrict__ z, const float* __restrict__ el,
                 const float* __restrict__ er, const int* __restrict__ src,
                 const int* __restrict__ rs, float* __restrict__ out)
{
  const int n = blockIdx.x, tid = threadIdx.x;
  const int s = rs[n], e = rs[n + 1];
  const bool active = (tid < 32);
  const float er_n = er[n];
  float acc = 0.f, den = 0.f;

  for (int k0 = s; k0 < e; k0 += 8) {
    const int kc = e - k0;
    #pragma unroll
    for (int kk = 0; kk < 8; ++kk) {
      if (kk < kc) {
        int si = src[k0 + kk];
        float v = el[si] + er_n;
        v = (v > 0.f) ? v : 0.2f * v;
        float wgt = __expf(v);
        if (active) acc += wgt * z[(size_t)si * 32 + tid];
        den += wgt;
      }
    }
  }
  if (active) out[(size_t)n * 32 + tid] = (e > s) ? (acc / den) : 0.f;
}

extern "C" void kernel_launch(void* const* d_in, const int* in_sizes, int n_in,
                              void* d_out, int out_size, void* d_ws, size_t ws_size,
                              hipStream_t stream)
{
  constexpr int N = 25000, E = 400000, K1 = 256, HF = 512, CLS = 32;
  const float* h   = (const float*)d_in[0];
  const int*   src = (const int*)d_in[1];
  const int*   dst = (const int*)d_in[2];
  const float* W1  = (const float*)d_in[3];
  const float* al1 = (const float*)d_in[4];
  const float* ar1 = (const float*)d_in[5];
  const float* W2  = (const float*)d_in[6];
  const float* al2 = (const float*)d_in[7];
  const float* ar2 = (const float*)d_in[8];
  const float* W3  = (const float*)d_in[9];
  const float* al3 = (const float*)d_in[10];
  const float* ar3 = (const float*)d_in[11];
  float* out = (float*)d_out;

  char* w = (char*)d_ws;
  auto take = [&](size_t bytes) {
    char* p = w;
    w += (bytes + 255) & ~(size_t)255;
    return p;
  };
  int*   rs = (int*)  take((size_t)(N + 1) * sizeof(int));
  float* el = (float*)take((size_t)N * 8 * sizeof(float));
  float* er = (float*)take((size_t)N * 8 * sizeof(float));
  float* z3 = (float*)take((size_t)N * CLS * sizeof(float));         // 3.2 MB
  u16*   zb = (u16*)  take((size_t)N * HF * sizeof(u16));            // 25.6 MB
  u16*   A2 = (u16*)  take((size_t)N * 2 * HF * sizeof(u16));        // 51.2 MB
  u16*   B2 = (u16*)  take((size_t)HF * 2 * HF * sizeof(u16));       // 1.05 MB

  rowstart_kernel<<<dim3((N + 1 + 255) / 256), 256, 0, stream>>>(dst, rs, N, E);

  const dim3 gemmGrid(HF / 128, (N + 127) / 128);   // 4 x 196

  // ---- Layer 1: K'=512 ----
  split_kernel<true ><<<dim3((N * K1 + 255) / 256), 256, 0, stream>>>(h,  A2, N * K1, K1);
  split_kernel<false><<<dim3((HF * K1 + 255) / 256), 256, 0, stream>>>(W1, B2, HF * K1, K1);
  gemm_bt_kernel<128, 1><<<gemmGrid, 256, 0, stream>>>(A2, B2, nullptr, zb, N, HF, 2 * K1, 2 * K1);
  elr_bf16_kernel<<<dim3((N * 8 + 255) / 256), 256, 0, stream>>>(zb, al1, ar1, el, er, N);
  agg_bf16_kernel<<<dim3(N), 64, 0, stream>>>(zb, el, er, src, rs, A2);

  // ---- Layer 2: K'=1024 ----
  split_kernel<false><<<dim3((HF * HF + 255) / 256), 256, 0, stream>>>(W2, B2, HF * HF, HF);
  gemm_bt_kernel<128, 1><<<gemmGrid, 256, 0, stream>>>(A2, B2, nullptr, zb, N, HF, 2 * HF, 2 * HF);
  elr_bf16_kernel<<<dim3((N * 8 + 255) / 256), 256, 0, stream>>>(zb, al2, ar2, el, er, N);
  agg_bf16_kernel<<<dim3(N), 64, 0, stream>>>(zb, el, er, src, rs, A2);

  // ---- Layer 3: K'=1024, Nout=32, split-K=4 + atomicAdd ----
  split_kernel<false><<<dim3((CLS * HF + 255) / 256), 256, 0, stream>>>(W3, B2, CLS * HF, HF);
  zero_kernel<<<dim3((N * CLS + 255) / 256), 256, 0, stream>>>(z3, N * CLS);
  gemm_bt_kernel<32, 2><<<dim3(4, (N + 127) / 128), 256, 0, stream>>>(A2, B2, z3, nullptr, N, CLS, 2 * HF, (2 * HF) / 4);
  elr_kernel<1, 32><<<dim3((N + 255) / 256), 256, 0, stream>>>(z3, al3, ar3, el, er, N);
  agg3_kernel<<<dim3(N), 64, 0, stream>>>(z3, el, er, src, rs, out);
}